// Round 1
// 125.606 us; speedup vs baseline: 1.0238x; 1.0238x over previous
//
#include <hip/hip_runtime.h>

// Problem constants
#define BB 256
#define PP 128
#define KK 16
#define HH 128
#define OO 256
#define EE 18      // 2*(C+F)
#define XCH 10     // C + F + 1 (coords, feats, mask)
#define BIGD 1000000000.0f
#define GPT 4      // points per block (= waves per block)

typedef __bf16 bf16x8 __attribute__((ext_vector_type(8)));
typedef __bf16 bf16x4 __attribute__((ext_vector_type(4)));
typedef float  f32x4  __attribute__((ext_vector_type(4)));

// ---------------------------------------------------------------------------
// Kernel 1: pack W2 and W1 into bf16 MFMA fragment order.
// W2p (B-frag, 16x16x32): [ct 16][ks 4][lane 64][j 8], elem = W2[ks*32+(l>>4)*8+j][ct*16+(l&15)]
// W1p (A-frag for h1^T = W1^T @ edge^T): [nt 8][lane 64][j 8],
//   elem = W1[k][nt*16+(l&15)] for k=(l>>4)*8+j < 18, else 0 (K padded to 32).
// ---------------------------------------------------------------------------
__global__ __launch_bounds__(256) void pack_w_kernel(const float* __restrict__ W1,
                                                     const float* __restrict__ W2,
                                                     __bf16* __restrict__ W2p,
                                                     __bf16* __restrict__ W1p) {
    const int t = blockIdx.x * 256 + threadIdx.x;  // 0 .. 36863
    if (t < 32768) {
        const int j  = t & 7;
        const int l  = (t >> 3) & 63;
        const int ks = (t >> 9) & 3;
        const int ct = t >> 11;
        const int row = ks * 32 + ((l >> 4) * 8) + j;
        const int col = ct * 16 + (l & 15);
        W2p[t] = (__bf16)W2[row * OO + col];
    } else {
        const int t2 = t - 32768;  // 0 .. 4095
        const int j  = t2 & 7;
        const int l  = (t2 >> 3) & 63;
        const int nt = t2 >> 9;
        const int k  = ((l >> 4) * 8) + j;
        const int n  = nt * 16 + (l & 15);
        W1p[t2] = (k < EE) ? (__bf16)W1[k * HH + n] : (__bf16)0.0f;
    }
}

// ---------------------------------------------------------------------------
// Kernel 2: fully-fused EdgeConv: per-block KNN + edge-MLP (all-MFMA).
// One block = 4 points = 4 waves.
//
// This revision targets occupancy (was ~23% ~= 2 blocks/CU, latency-bound:
// MfmaUtil 13 + VALUBusy 30, HBM 7%):
//  - GEMM2 split into two ct-halves: acc live-set 64 -> 32 f32 regs
//    (unified VGPR+AGPR total target <= 128 -> 4 waves/SIMD). af re-read
//    from LDS per half (+16 ds_read_b128/wave, cheap).
//  - sb1/sb2/smask LDS staging + barrier 1 REMOVED: b1 read as broadcast
//    float4 per nt, b2 as scalar per ct, masks straight from x (all L1-hot).
//    One __syncthreads per block (sh1A write->read) instead of two.
//  - W1p fragments + center row hoisted ABOVE the serial radix-select chain
//    so their VMEM latency hides under the ballot/popc dependency chain.
// Numerics identical to the 128.7us version (same op order everywhere).
// ---------------------------------------------------------------------------
__global__ __launch_bounds__(256, 4) void mlp_kernel(const float* __restrict__ x,
                                                     const __bf16* __restrict__ W1p,
                                                     const float* __restrict__ b1,
                                                     const __bf16* __restrict__ W2p,
                                                     const float* __restrict__ b2,
                                                     float* __restrict__ out) {
    __shared__ __bf16 sh1A[16 * 64 * 8];  // [ks*4+g][lane][j], 16 KB
    __shared__ int    sknn[GPT][KK];      // per-wave winner slots

    const int tid = threadIdx.x;
    const int lane = tid & 63;
    const int w = tid >> 6;
    const int quad = lane >> 4;
    const int lcol = lane & 15;

    const int pbase = blockIdx.x * GPT;
    const int bidx = pbase >> 7;
    const int i0 = pbase & (PP - 1);
    const float* xb = x + (size_t)bidx * PP * XCH;
    float* outrow = out + (size_t)pbase * (OO + 1);

    // masks straight from x (L1-hot): lane's quad-point mask + wave's point mask
    const float mq = xb[(i0 + quad) * XCH + (XCH - 1)];
    const int i = i0 + w;

    if (__all(mq == 0.0f)) {
        // out is re-poisoned before every launch: must write zeros
        for (int o = tid; o < GPT * (OO + 1); o += 256) outrow[o] = 0.0f;
        return;  // block-uniform (every wave sees all 4 masks): no barrier mismatch
    }

    // ---- prefetch: GEMM1 A-fragments + center row (independent of KNN) ----
    bf16x8 wf[8];
#pragma unroll
    for (int nt = 0; nt < 8; ++nt)
        wf[nt] = *(const bf16x8*)&W1p[(size_t)((nt * 64 + lane) * 8)];

    const float* ci = xb + i * XCH;   // wave-uniform address
    const float2 a01 = *(const float2*)(ci + 0);
    const float2 a23 = *(const float2*)(ci + 2);
    const float2 a45 = *(const float2*)(ci + 4);
    const float2 a67 = *(const float2*)(ci + 6);
    const float  a8  = ci[8];
    const float  mw  = ci[XCH - 1];   // this wave's point mask (wave-uniform)

    // ================= KNN: wave w selects 16 neighbors of point i0+w ======
    // RADIX-4 select over 128 candidates (lane l owns j=l and j=l+64).
    // key = (d_bits << 7) | j : unique, ascending key order == lexicographic
    // (d, j) == jax.lax.top_k's stable order (d >= 0 so fp32 bits are
    // monotone as uint). Self is the unique d=0 min == the dropped "nearest",
    // so exclude it and select the top-16 SET. dist2 uses __fmul_rn/__fadd_rn
    // to match numpy bit-exact.
    if (mw != 0.0f) {   // wave-uniform
        const float cix = a01.x;
        const float ciy = a01.y;

        const int j0 = lane, j1 = lane + 64;
        float d0, d1;
        {
            const float2 c0 = *(const float2*)(xb + j0 * XCH);
            const float m0 = xb[j0 * XCH + (XCH - 1)];
            float dx = cix - c0.x, dy = ciy - c0.y;
            d0 = __fadd_rn(__fmul_rn(dx, dx), __fmul_rn(dy, dy));
            if (m0 <= 0.0f || j0 == i) d0 = BIGD;
        }
        {
            const float2 c1 = *(const float2*)(xb + j1 * XCH);
            const float m1 = xb[j1 * XCH + (XCH - 1)];
            float dx = cix - c1.x, dy = ciy - c1.y;
            d1 = __fadd_rn(__fmul_rn(dx, dx), __fmul_rn(dy, dy));
            if (m1 <= 0.0f || j1 == i) d1 = BIGD;
        }

        const unsigned d0b = __float_as_uint(d0);
        const unsigned d1b = __float_as_uint(d1);

        unsigned long long A0 = ~0ull, A1 = ~0ull, W0 = 0ull, W1 = 0ull;
        int need = KK;
        int asz = 2 * 64;   // |A|

        auto step = [&](unsigned long long q0, unsigned long long q1) {
            const unsigned long long z0 = A0 & q0;
            const unsigned long long z1 = A1 & q1;
            const int c = __popcll(z0) + __popcll(z1);
            if (c == need) { W0 |= z0; W1 |= z1; A0 = A1 = 0ull; need = 0; }
            else if (c > need) { A0 = z0; A1 = z1; asz = c; }
            else { W0 |= z0; W1 |= z1; need -= c; A0 &= ~z0; A1 &= ~z1; asz -= c; }
        };

        // phase A: radix-4 digits over d bits (30,29),(28,27),...,(2,1)
#pragma unroll 1
        for (int t = 14; t >= 0; --t) {
            const unsigned dg0 = (d0b >> (2 * t + 1)) & 3u;
            const unsigned dg1 = (d1b >> (2 * t + 1)) & 3u;
            const unsigned long long p0_0  = __ballot(dg0 == 0u);
            const unsigned long long p1_0  = __ballot(dg1 == 0u);
            const unsigned long long p0_01 = __ballot(dg0 <= 1u);
            const unsigned long long p1_01 = __ballot(dg1 <= 1u);
            const unsigned long long p0_02 = __ballot(dg0 <= 2u);
            const unsigned long long p1_02 = __ballot(dg1 <= 2u);
            const unsigned long long z0_0  = A0 & p0_0,  z1_0  = A1 & p1_0;
            const unsigned long long z0_01 = A0 & p0_01, z1_01 = A1 & p1_01;
            const unsigned long long z0_02 = A0 & p0_02, z1_02 = A1 & p1_02;
            const int c0  = __popcll(z0_0)  + __popcll(z1_0);
            const int c01 = __popcll(z0_01) + __popcll(z1_01);
            const int c02 = __popcll(z0_02) + __popcll(z1_02);
            if (c0 >= need) {
                A0 = z0_0; A1 = z1_0; asz = c0;
            } else if (c01 >= need) {
                W0 |= z0_0; W1 |= z1_0; need -= c0;
                A0 = z0_01 & ~p0_0; A1 = z1_01 & ~p1_0; asz = c01 - c0;
            } else if (c02 >= need) {
                W0 |= z0_01; W1 |= z1_01; need -= c01;
                A0 = z0_02 & ~p0_01; A1 = z1_02 & ~p1_01; asz = c02 - c01;
            } else {
                W0 |= z0_02; W1 |= z1_02; need -= c02;
                A0 &= ~p0_02; A1 &= ~p1_02; asz -= c02;
            }
            if (asz == need) { W0 |= A0; W1 |= A1; A0 = A1 = 0ull; need = 0; break; }
        }
        // phase A': last d bit (bit 0)
        if (need) {
            const unsigned long long q0 = __ballot((d0b & 1u) == 0u);
            const unsigned long long q1 = __ballot((d1b & 1u) == 0u);
            step(q0, q1);
        }
        // phase B: index bits 6..0 (j0 = lane, j1 = lane+64): constant masks
        if (need) step(~0ull, 0ull);  // bit 6: all j0 are 0, all j1 are 1
        {
            const unsigned long long M5 = 0x00000000FFFFFFFFull;
            const unsigned long long M4 = 0x0000FFFF0000FFFFull;
            const unsigned long long M3 = 0x00FF00FF00FF00FFull;
            const unsigned long long M2 = 0x0F0F0F0F0F0F0F0Full;
            const unsigned long long M1 = 0x3333333333333333ull;
            const unsigned long long M0 = 0x5555555555555555ull;
            if (need) step(M5, M5);
            if (need) step(M4, M4);
            if (need) step(M3, M3);
            if (need) step(M2, M2);
            if (need) step(M1, M1);
            if (need) step(M0, M0);
        }
        W0 |= A0; W1 |= A1;  // keys unique => remaining actives = the rest

        unsigned int mb0 = __builtin_amdgcn_mbcnt_lo((unsigned)(W0 & 0xffffffffull), 0u);
        mb0 = __builtin_amdgcn_mbcnt_hi((unsigned)(W0 >> 32), mb0);
        unsigned int mb1 = __builtin_amdgcn_mbcnt_lo((unsigned)(W1 & 0xffffffffull), 0u);
        mb1 = __builtin_amdgcn_mbcnt_hi((unsigned)(W1 >> 32), mb1);
        const int base1 = __popcll(W0);

        if ((W0 >> lane) & 1ull) sknn[w][mb0] = j0;
        if ((W1 >> lane) & 1ull) sknn[w][base1 + mb1] = j1;
    } else {
        if (lane < KK) sknn[w][lane] = 0;  // dummy valid indices (row masked to 0)
    }
    // NO barrier: wave w reads only its own sknn[w] (lgkmcnt-ordered)

    // ================= edge build -> GEMM1 B-fragment (registers only) =====
    // this thread: point g=w, neighbor slot lcol, channel block quad (8 ch)
    const int jn = sknn[w][lcol];
    const float* cj = xb + jn * XCH;
    const float2 n01 = *(const float2*)(cj + 0);
    const float2 n23 = *(const float2*)(cj + 2);
    const float2 n45 = *(const float2*)(cj + 4);
    const float2 n67 = *(const float2*)(cj + 6);
    const float  n8  = cj[8];

    float v[8];
#pragma unroll
    for (int e = 0; e < 8; ++e) v[e] = 0.0f;
    if (quad == 0) {           // channels 0..7 = center ch 0..7
        v[0] = a01.x; v[1] = a01.y; v[2] = a23.x; v[3] = a23.y;
        v[4] = a45.x; v[5] = a45.y; v[6] = a67.x; v[7] = a67.y;
    } else if (quad == 1) {    // ch 8 = center ch8; ch 9..15 = diff ch 0..6
        v[0] = a8;
        v[1] = n01.x - a01.x; v[2] = n01.y - a01.y;
        v[3] = n23.x - a23.x; v[4] = n23.y - a23.y;
        v[5] = n45.x - a45.x; v[6] = n45.y - a45.y;
        v[7] = n67.x - a67.x;
    } else if (quad == 2) {    // ch 16 = diff ch7; ch 17 = diff ch8; rest 0
        v[0] = n67.y - a67.y;
        v[1] = n8 - a8;
    }                          // quad 3: zero padding (K 18 -> 32)

    bf16x8 ef;
#pragma unroll
    for (int e = 0; e < 8; ++e) ef[e] = (__bf16)v[e];

    // ---- GEMM1 (MFMA): h1^T tiles; A = wf (prefetched), B = ef ----
    const f32x4 z4 = {0.0f, 0.0f, 0.0f, 0.0f};
    f32x4 h[8];
#pragma unroll
    for (int nt = 0; nt < 8; ++nt)
        h[nt] = __builtin_amdgcn_mfma_f32_16x16x32_bf16(wf[nt], ef, z4, 0, 0, 0);

    // ---- epilogue 1: relu(+b1), write bf16 into GEMM2 A-frag order ----
    // b1 read directly as broadcast float4 (L1-hot, no LDS staging/barrier).
#pragma unroll
    for (int nt = 0; nt < 8; ++nt) {
        const int ks = nt >> 1;
        const int lp = (((nt * 2 + (quad >> 1)) & 3) << 4) | lcol;
        const f32x4 b1v = *(const f32x4*)&b1[nt * 16 + quad * 4];
        bf16x4 hv;
#pragma unroll
        for (int r = 0; r < 4; ++r)
            hv[r] = (__bf16)fmaxf(h[nt][r] + b1v[r], 0.0f);
        *(bf16x4*)&sh1A[((ks * GPT + w) * 64 + lp) * 8 + (quad & 1) * 4] = hv;
    }
    __syncthreads();

    // ---- GEMM2 (MFMA): h2[64][256] = relu(h1 @ W2 + b2), fused K-mean ----
    // Split into two ct-halves: acc live-set 32 f32 regs (not 64); af re-read
    // per half from LDS. Per-(g,ct) ks-order unchanged -> bit-identical.
    const float mscale = mq * (1.0f / KK);
#pragma unroll
    for (int ch = 0; ch < 2; ++ch) {
        f32x4 acc[GPT][2];
#pragma unroll
        for (int g = 0; g < GPT; ++g) { acc[g][0] = z4; acc[g][1] = z4; }

#pragma unroll
        for (int ks = 0; ks < 4; ++ks) {
            bf16x8 af[GPT], bfr[2];
#pragma unroll
            for (int g = 0; g < GPT; ++g)
                af[g] = *(const bf16x8*)&sh1A[((ks * GPT + g) * 64 + lane) * 8];
#pragma unroll
            for (int c = 0; c < 2; ++c) {
                const int ct = ch * 2 + c;
                bfr[c] = *(const bf16x8*)&W2p[(size_t)((((w * 4 + ct) * 4 + ks) * 64 + lane) * 8)];
            }
#pragma unroll
            for (int g = 0; g < GPT; ++g)
#pragma unroll
                for (int c = 0; c < 2; ++c)
                    acc[g][c] = __builtin_amdgcn_mfma_f32_16x16x32_bf16(
                        af[g], bfr[c], acc[g][c], 0, 0, 0);
        }

        // ---- epilogue 2: relu(+b2), K-sum = tile column sum via shuffles ----
        // C layout: col=lcol, row=quad*4+r; tile g's 16 rows = point g's K
        // neighbors. Partial over 4 rows in-lane, then fold quads (xor 16, 32).
#pragma unroll
        for (int c = 0; c < 2; ++c) {
            const int ct = ch * 2 + c;
            const int col = w * 64 + ct * 16 + lcol;
            const float bc = b2[col];
            float val = 0.0f;
#pragma unroll
            for (int g = 0; g < GPT; ++g) {
                float s = 0.0f;
#pragma unroll
                for (int r = 0; r < 4; ++r) s += fmaxf(acc[g][c][r] + bc, 0.0f);
                s += __shfl_xor(s, 16, 64);
                s += __shfl_xor(s, 32, 64);
                if (quad == g) val = s;   // lane (quad=g, lcol) keeps point g
            }
            outrow[(size_t)quad * (OO + 1) + col] = val * mscale;
        }
    }
    if (tid < GPT) outrow[(size_t)tid * (OO + 1) + OO] = xb[(i0 + tid) * XCH + (XCH - 1)];
}

extern "C" void kernel_launch(void* const* d_in, const int* in_sizes, int n_in,
                              void* d_out, int out_size, void* d_ws, size_t ws_size,
                              hipStream_t stream) {
    const float* x  = (const float*)d_in[0];
    const float* W1 = (const float*)d_in[1];
    const float* b1 = (const float*)d_in[2];
    const float* W2 = (const float*)d_in[3];
    const float* b2 = (const float*)d_in[4];
    float* out = (float*)d_out;

    __bf16* W2p = (__bf16*)d_ws;                    // 64 KB
    __bf16* W1p = (__bf16*)((char*)d_ws + 65536);   // 8 KB

    pack_w_kernel<<<144, 256, 0, stream>>>(W1, W2, W2p, W1p);

    const int nblocks = (BB * PP) / GPT;  // 8192
    mlp_kernel<<<nblocks, 256, 0, stream>>>(x, W1p, b1, W2p, b2, out);
}